// Round 8
// baseline (331.470 us; speedup 1.0000x reference)
//
#include <hip/hip_runtime.h>
#include <hip/hip_bf16.h>
#include <stdint.h>

constexpr int BB  = 64;    // batch
constexpr int SS  = 512;   // seq len
constexpr int HH  = 768;   // hidden
constexpr int NL  = 9;     // labels
constexpr int NROWS = BB * SS;          // 32768
constexpr int EMN   = SS * NL;          // 4608 emissions per batch
constexpr int NSEG  = 8;                // time segments for parallel lognorm
constexpr float NEG  = -1e30f;

__device__ __forceinline__ float readlane_f(float v, int lane) {
  union { float f; int i; } u;
  u.f = v;
  u.i = __builtin_amdgcn_readlane(u.i, lane);
  return u.f;
}

// ---------------------------------------------------------------------------
// Kernel 1: logits = hidden @ W + b. 512 one-wave blocks, 64 rows each.
// Lane = row. K-chunks of 32 staged via register->LDS (coalesced loads),
// W read wave-uniform (scalar path). No butterfly, no spills.
// Blocks 0..63 also compute lens[b].
// ---------------------------------------------------------------------------
__global__ __launch_bounds__(64) void logits_kernel(
    const float* __restrict__ hidden, const float* __restrict__ W,
    const float* __restrict__ bias, const int* __restrict__ mask,
    float* __restrict__ logits, int* __restrict__ lens) {
  __shared__ float tile[64 * 33];   // stride 33: conflict-free, 8448 B
  const int tid = threadIdx.x;

  if (blockIdx.x < 64) {
    const int4* mp = (const int4*)(mask + blockIdx.x * SS);
    const int4 a = mp[tid];
    const int4 c = mp[tid + 64];
    int lsum = a.x + a.y + a.z + a.w + c.x + c.y + c.z + c.w;
#pragma unroll
    for (int off = 32; off >= 1; off >>= 1) lsum += __shfl_xor(lsum, off, 64);
    if (tid == 0) lens[blockIdx.x] = lsum;
  }

  const int rowbase = blockIdx.x * 64;
  const float* hbase = hidden + (size_t)rowbase * HH;
  float acc[NL];
#pragma unroll
  for (int l = 0; l < NL; ++l) acc[l] = 0.0f;

  float r[32];
#pragma unroll
  for (int i = 0; i < 32; ++i) {          // prefetch chunk 0
    const int e = i * 64 + tid;           // row = e>>5 (2 rows per load), k = e&31
    r[i] = hbase[(e >> 5) * HH + (e & 31)];
  }
  for (int c = 0; c < 24; ++c) {
    // single-wave block: DS ops are in program order, no barrier needed
#pragma unroll
    for (int i = 0; i < 32; ++i) {
      const int e = i * 64 + tid;
      tile[(e >> 5) * 33 + (e & 31)] = r[i];
    }
    if (c < 23) {
      const float* hb = hbase + (c + 1) * 32;
#pragma unroll
      for (int i = 0; i < 32; ++i) {
        const int e = i * 64 + tid;
        r[i] = hb[(e >> 5) * HH + (e & 31)];
      }
    }
    const float* wrow = W + c * 32 * NL;  // wave-uniform -> scalar loads
#pragma unroll
    for (int k = 0; k < 32; ++k) {
      const float h = tile[tid * 33 + k];
#pragma unroll
      for (int l = 0; l < NL; ++l) acc[l] += h * wrow[k * NL + l];
    }
  }
  float* orow = logits + (size_t)(rowbase + tid) * NL;
#pragma unroll
  for (int l = 0; l < NL; ++l) orow[l] = acc[l] + bias[l];
}

// ---------------------------------------------------------------------------
// Kernel 2: scan kernel, 1664 one-wave blocks.
//   blk   0..  63 : viterbi — two-pass: serial VALUE scan (no argmax in the
//                   chain), then PARALLEL bp recompute + chunk backtrace
//   blk  64.. 127 : numerator (gold-path score)
//   blk 128..1663 : lognorm segment scans, 3 basis chains per wave
// LDS 19.3 KB -> 8 blocks/CU -> all 1664 co-resident.
// ---------------------------------------------------------------------------
__global__ __launch_bounds__(64) void scan_kernel(
    const float* __restrict__ logits, const int* __restrict__ labels,
    const float* __restrict__ start_t, const float* __restrict__ end_t,
    const float* __restrict__ trans, float* __restrict__ out,
    float* __restrict__ num_den, const int* __restrict__ lens,
    float* __restrict__ segmat) {
  __shared__ __align__(16) unsigned char smem[19280];
  // viterbi:   svec = float[4608] @0, tags @18432, tr_s = float[81] @18960
  // numerator: lab  = int[512]   @0

  const int blk = blockIdx.x;
  const int tid = threadIdx.x;
  const int j   = (tid < NL) ? tid : NL - 1;

  if (blk < 64) {
    // ================= viterbi =================
    float* svec = (float*)smem;
    unsigned char* tags_s = smem + 18432;
    float* tr_s = (float*)(smem + 18960);
    const int b   = blk;
    const int len = lens[b];
    const float* emb = logits + (size_t)b * EMN;
    for (int i = tid; i < NL * NL; i += 64) tr_s[i] = trans[i];
    float tc[NL];
#pragma unroll
    for (int i = 0; i < NL; ++i) tc[i] = trans[i * NL + j];
    float s[NL];
#pragma unroll
    for (int i = 0; i < NL; ++i) s[i] = start_t[i] + emb[i];
    {
      const float myv = start_t[j] + emb[j];   // == s[j] bitwise
      if (tid < NL) svec[tid] = myv;
    }
    // ---- pass 1: serial value scan (max is exact; argmax deferred) ----
    float eA = emb[1 * NL + j], eB = emb[2 * NL + j];
    float eC = emb[3 * NL + j], eD = emb[4 * NL + j];
    for (int t = 1; t < len; ++t) {
      float c[NL];
#pragma unroll
      for (int i = 0; i < NL; ++i) c[i] = s[i] + tc[i];
      const float m012 = fmaxf(fmaxf(c[0], c[1]), c[2]);
      const float m345 = fmaxf(fmaxf(c[3], c[4]), c[5]);
      const float m678 = fmaxf(fmaxf(c[6], c[7]), c[8]);
      const float best = fmaxf(fmaxf(m012, m345), m678);
      const float nxt = best + eA;
      if (tid < NL) svec[t * NL + tid] = nxt;
#pragma unroll
      for (int i = 0; i < NL; ++i) s[i] = readlane_f(nxt, i);
      eA = eB; eB = eC; eC = eD;
      eD = emb[(t + 4) * NL + j];   // overrun stays inside ws: safe
    }
    float bv = s[0] + end_t[0];
    int   bl = 0;
#pragma unroll
    for (int i = 1; i < NL; ++i) {
      const float cc = s[i] + end_t[i];
      if (cc > bv) { bv = cc; bl = i; }
    }
    __syncthreads();

    // ---- pass 2: parallel bp recompute (bit-identical adds + first-max) ----
    // lane c covers t in [8c+1, 8c+8]; bp packed as 9 nibbles per step.
    uint64_t bpt[9];
#pragma unroll
    for (int k = 1; k <= 8; ++k) {
      const int t = 8 * tid + k;              // t in [1, 512]; svec[t-1] valid
      float sp[NL];
#pragma unroll
      for (int i = 0; i < NL; ++i) sp[i] = svec[(t - 1) * NL + i];
      uint64_t nib = 0;
#pragma unroll
      for (int jj = 0; jj < NL; ++jj) {
        float cc[NL];
#pragma unroll
        for (int i = 0; i < NL; ++i) cc[i] = sp[i] + tr_s[i * NL + jj];
        const bool b01 = cc[0] >= cc[1], b23 = cc[2] >= cc[3];
        const bool b45 = cc[4] >= cc[5], b67 = cc[6] >= cc[7];
        const float v01 = b01 ? cc[0] : cc[1]; const int i01 = b01 ? 0 : 1;
        const float v23 = b23 ? cc[2] : cc[3]; const int i23 = b23 ? 2 : 3;
        const float v45 = b45 ? cc[4] : cc[5]; const int i45 = b45 ? 4 : 5;
        const float v67 = b67 ? cc[6] : cc[7]; const int i67 = b67 ? 6 : 7;
        const bool bA = v01 >= v23, bB = v45 >= v67;
        const float vA = bA ? v01 : v23; const int iA = bA ? i01 : i23;
        const float vB = bB ? v45 : v67; const int iB = bB ? i45 : i67;
        const bool bC = vA >= vB;
        const float vC = bC ? vA : vB; const int iC = bC ? iA : iB;
        const bool bD = vC >= cc[8];
        const int arg = bD ? iC : 8;
        nib |= (uint64_t)arg << (4 * jj);
      }
      bpt[k] = nib;
    }
    // ---- phase A: compose this lane's 8 steps into a 9-nibble map ----
    uint64_t C = 0x876543210ULL;
#pragma unroll
    for (int k = 1; k <= 8; ++k) {
      const int t = 8 * tid + k;
      uint64_t nc = 0;
#pragma unroll
      for (int x = 0; x < 9; ++x) {
        const int g = (int)((bpt[k] >> (4 * x)) & 15);
        nc |= ((C >> (4 * g)) & 15ULL) << (4 * x);
      }
      C = (t < len) ? nc : C;
    }
    // ---- phase B: scalar chase over the 64 chunk maps ----
    const uint32_t Clo = (uint32_t)C, Chi = (uint32_t)(C >> 32);
    uint32_t cur = (uint32_t)bl;
    int bnd = 0;
#pragma unroll
    for (int c = 63; c >= 0; --c) {
      bnd = (tid == c) ? (int)cur : bnd;
      const uint32_t lo = (uint32_t)__builtin_amdgcn_readlane((int)Clo, c);
      const uint32_t hi = (uint32_t)__builtin_amdgcn_readlane((int)Chi, c);
      const uint64_t cc = ((uint64_t)hi << 32) | lo;
      cur = (uint32_t)((cc >> (4 * cur)) & 15u);
    }
    // ---- phase C: re-walk own 8 steps from registers ----
    int tag = bnd;
#pragma unroll
    for (int k = 8; k >= 1; --k) {
      const int t = 8 * tid + k;
      const int nt = (int)((bpt[k] >> (4 * tag)) & 15);
      tag = (t < len) ? nt : tag;
      tags_s[t - 1] = (unsigned char)tag;
    }
    __syncthreads();
    for (int i = tid; i < EMN; i += 64) {
      const int t = i / NL;
      const int l = i - t * NL;
      out[1 + (size_t)b * EMN + i] =
          (t < len && l == (int)tags_s[t]) ? 1.0f : 0.0f;
    }

  } else if (blk < 128) {
    // ================= numerator =================
    int* lab = (int*)smem;
    const int b   = blk - 64;
    const int len = lens[b];
    const float* emb = logits + (size_t)b * EMN;
    for (int t = tid; t < SS; t += 64) {
      const int v = labels[b * SS + t];
      lab[t] = (v == -100) ? 0 : v;
    }
    __syncthreads();
    float contrib = 0.0f;
    for (int t = tid; t < SS; t += 64) {
      if (t >= 1 && t < len)
        contrib += emb[t * NL + lab[t]] + trans[lab[t - 1] * NL + lab[t]];
    }
#pragma unroll
    for (int off = 32; off >= 1; off >>= 1)
      contrib += __shfl_xor(contrib, off, 64);
    if (tid == 0) {
      const int l0 = lab[0];
      num_den[b] = start_t[l0] + emb[l0] + contrib + end_t[lab[len - 1]];
    }

  } else {
    // ================= lognorm segment scan, 3 chains per wave =================
    const int id   = blk - 128;        // 0..1535
    const int pair = id / 3;
    const int wv   = id - pair * 3;
    const int b    = pair >> 3;
    const int sg   = pair & 7;
    const int e0   = 3 * wv;
    const int len  = lens[b];
    const float* emb = logits + (size_t)b * EMN;
    float tc[NL];
#pragma unroll
    for (int i = 0; i < NL; ++i) tc[i] = trans[i * NL + j];
    float s0[NL], s1[NL], s2[NL];
#pragma unroll
    for (int i = 0; i < NL; ++i) {
      s0[i] = (i == e0)     ? 0.0f : NEG;
      s1[i] = (i == e0 + 1) ? 0.0f : NEG;
      s2[i] = (i == e0 + 2) ? 0.0f : NEG;
    }
    float my0 = (j == e0)     ? 0.0f : NEG;
    float my1 = (j == e0 + 1) ? 0.0f : NEG;
    float my2 = (j == e0 + 2) ? 0.0f : NEG;
    const int tbeg  = 64 * sg + 1;
    const int tlast = (64 * sg + 64 < 511) ? 64 * sg + 64 : 511;
    float eA = emb[tbeg * NL + j],       eB = emb[(tbeg + 1) * NL + j];
    float eC = emb[(tbeg + 2) * NL + j], eD = emb[(tbeg + 3) * NL + j];
    for (int t = tbeg; t <= tlast; ++t) {
      if (t >= len) break;
      float c0[NL], c1[NL], c2[NL];
#pragma unroll
      for (int i = 0; i < NL; ++i) {
        c0[i] = s0[i] + tc[i];
        c1[i] = s1[i] + tc[i];
        c2[i] = s2[i] + tc[i];
      }
      const float m0 = fmaxf(fmaxf(fmaxf(fmaxf(c0[0], c0[1]), fmaxf(c0[2], c0[3])),
                                   fmaxf(fmaxf(c0[4], c0[5]), fmaxf(c0[6], c0[7]))), c0[8]);
      const float m1 = fmaxf(fmaxf(fmaxf(fmaxf(c1[0], c1[1]), fmaxf(c1[2], c1[3])),
                                   fmaxf(fmaxf(c1[4], c1[5]), fmaxf(c1[6], c1[7]))), c1[8]);
      const float m2 = fmaxf(fmaxf(fmaxf(fmaxf(c2[0], c2[1]), fmaxf(c2[2], c2[3])),
                                   fmaxf(fmaxf(c2[4], c2[5]), fmaxf(c2[6], c2[7]))), c2[8]);
      float u0 = 0.0f, u1 = 0.0f, u2 = 0.0f;
#pragma unroll
      for (int i = 0; i < NL; ++i) {
        u0 += __expf(c0[i] - m0);
        u1 += __expf(c1[i] - m1);
        u2 += __expf(c2[i] - m2);
      }
      my0 = m0 + __logf(u0) + eA;
      my1 = m1 + __logf(u1) + eA;
      my2 = m2 + __logf(u2) + eA;
#pragma unroll
      for (int i = 0; i < NL; ++i) {
        s0[i] = readlane_f(my0, i);
        s1[i] = readlane_f(my1, i);
        s2[i] = readlane_f(my2, i);
      }
      eA = eB; eB = eC; eC = eD;
      eD = emb[(t + 4) * NL + j];
    }
    if (tid < NL) {
      float* M = segmat + (size_t)(b * NSEG + sg) * 81;
      M[(e0    ) * NL + tid] = my0;
      M[(e0 + 1) * NL + tid] = my1;
      M[(e0 + 2) * NL + tid] = my2;
    }
  }
}

// ---------------------------------------------------------------------------
// Kernel 3: combine + loss — chain the 8 segment matrices per batch, get
// den = logsumexp(v + end_t), atomically accumulate (den-num)/64.
// ---------------------------------------------------------------------------
__global__ __launch_bounds__(64) void combine_kernel(
    const float* __restrict__ logits, const float* __restrict__ segmat,
    const float* __restrict__ start_t, const float* __restrict__ end_t,
    const float* __restrict__ num_den, float* __restrict__ out) {
  const int b   = blockIdx.x;
  const int tid = threadIdx.x;
  const int j   = (tid < NL) ? tid : NL - 1;
  float s[NL];
#pragma unroll
  for (int i = 0; i < NL; ++i) s[i] = start_t[i] + logits[(size_t)b * EMN + i];
  float mcur[NL], mnxt[NL];
  {
    const float* M = segmat + (size_t)(b * NSEG) * 81;
#pragma unroll
    for (int i = 0; i < NL; ++i) mcur[i] = M[i * NL + j];
  }
  for (int sg = 0; sg < NSEG; ++sg) {
    if (sg + 1 < NSEG) {
      const float* M = segmat + (size_t)(b * NSEG + sg + 1) * 81;
#pragma unroll
      for (int i = 0; i < NL; ++i) mnxt[i] = M[i * NL + j];
    }
    float c[NL];
#pragma unroll
    for (int i = 0; i < NL; ++i) c[i] = s[i] + mcur[i];
    const float x01 = fmaxf(c[0], c[1]), x23 = fmaxf(c[2], c[3]);
    const float x45 = fmaxf(c[4], c[5]), x67 = fmaxf(c[6], c[7]);
    const float m = fmaxf(fmaxf(fmaxf(x01, x23), fmaxf(x45, x67)), c[8]);
    float sum = 0.0f;
#pragma unroll
    for (int i = 0; i < NL; ++i) sum += __expf(c[i] - m);
    const float nxt = m + __logf(sum);
#pragma unroll
    for (int i = 0; i < NL; ++i) s[i] = readlane_f(nxt, i);
#pragma unroll
    for (int i = 0; i < NL; ++i) mcur[i] = mnxt[i];
  }
  float c[NL];
#pragma unroll
  for (int i = 0; i < NL; ++i) c[i] = s[i] + end_t[i];
  const float x01 = fmaxf(c[0], c[1]), x23 = fmaxf(c[2], c[3]);
  const float x45 = fmaxf(c[4], c[5]), x67 = fmaxf(c[6], c[7]);
  const float m = fmaxf(fmaxf(fmaxf(x01, x23), fmaxf(x45, x67)), c[8]);
  float sum = 0.0f;
#pragma unroll
  for (int i = 0; i < NL; ++i) sum += __expf(c[i] - m);
  if (tid == 0) {
    const float den = m + __logf(sum);
    atomicAdd(out, (den - num_den[b]) * (1.0f / 64.0f));
  }
}

extern "C" void kernel_launch(void* const* d_in, const int* in_sizes, int n_in,
                              void* d_out, int out_size, void* d_ws, size_t ws_size,
                              hipStream_t stream) {
  const float* hidden  = (const float*)d_in[0];
  const int*   mask    = (const int*)d_in[1];
  const int*   labels  = (const int*)d_in[2];
  const float* W       = (const float*)d_in[3];
  const float* bias    = (const float*)d_in[4];
  const float* start_t = (const float*)d_in[5];
  const float* end_t   = (const float*)d_in[6];
  const float* trans   = (const float*)d_in[7];
  float* out = (float*)d_out;

  float* logits  = (float*)d_ws;                      // 294912 floats
  float* segmat  = logits + (size_t)NROWS * NL;       // 64*8*81 floats
  float* num_den = segmat + (size_t)BB * NSEG * 81;   // 128 floats
  int*   lens    = (int*)(num_den + 128);             // 64 ints

  hipMemsetAsync(out, 0, sizeof(float), stream);      // zero loss accumulator
  logits_kernel<<<512, 64, 0, stream>>>(hidden, W, bias, mask, logits, lens);
  scan_kernel<<<1664, 64, 0, stream>>>(logits, labels, start_t, end_t, trans,
                                       out, num_den, lens, segmat);
  combine_kernel<<<64, 64, 0, stream>>>(logits, segmat, start_t, end_t,
                                        num_den, out);
}

// Round 9
// 264.097 us; speedup vs baseline: 1.2551x; 1.2551x over previous
//
#include <hip/hip_runtime.h>
#include <hip/hip_bf16.h>
#include <stdint.h>

constexpr int BB  = 64;    // batch
constexpr int SS  = 512;   // seq len
constexpr int HH  = 768;   // hidden
constexpr int NL  = 9;     // labels
constexpr int NROWS = BB * SS;          // 32768
constexpr int EMN   = SS * NL;          // 4608 emissions per batch
constexpr int NSEG  = 8;                // time segments for parallel lognorm
constexpr float NEG  = -1e30f;

__device__ __forceinline__ float readlane_f(float v, int lane) {
  union { float f; int i; } u;
  u.f = v;
  u.i = __builtin_amdgcn_readlane(u.i, lane);
  return u.f;
}

// ---------------------------------------------------------------------------
// Kernel 1: logits = hidden @ W + b.
// 512 blocks x 256 threads (2048 waves, 8/CU). Block = 64 rows.
// wave = K-segment (192 of 768, wave-uniform), lane = row.
// W lives transposed in LDS (wt[l][k]); all W reads are wave-uniform
// ds_read_b128 broadcasts (no scalar-load/LDS lgkmcnt hazard — R8's mistake).
// hidden read as per-lane sequential float4 (L1/L2-mediated line reuse).
// Per-seg partials combined via LDS. Blocks 0..63 also compute lens[b].
// ---------------------------------------------------------------------------
__global__ __launch_bounds__(256) void logits_kernel(
    const float* __restrict__ hidden, const float* __restrict__ W,
    const float* __restrict__ bias, const int* __restrict__ mask,
    float* __restrict__ logits, int* __restrict__ lens) {
  __shared__ float wt[NL * HH];        // [l][k] transposed W, 27648 B
  __shared__ float part[4][64][10];    // per-seg partials (pad 9->10), 10240 B
  const int tid  = threadIdx.x;
  const int lane = tid & 63;
  const int seg  = tid >> 6;           // 0..3 == wave id (wave-uniform)

  if (blockIdx.x < 64 && tid < 64) {   // lens[b] = sum(mask[b])
    const int4* mp = (const int4*)(mask + blockIdx.x * SS);
    const int4 a = mp[tid];
    const int4 c = mp[tid + 64];
    int lsum = a.x + a.y + a.z + a.w + c.x + c.y + c.z + c.w;
#pragma unroll
    for (int off = 32; off >= 1; off >>= 1) lsum += __shfl_xor(lsum, off, 64);
    if (tid == 0) lens[blockIdx.x] = lsum;
  }

  // Stage W transposed into LDS (one-time; coalesced global reads)
  for (int idx = tid; idx < HH * NL; idx += 256) {
    const int k = idx / NL, l = idx - k * NL;
    wt[l * HH + k] = W[idx];
  }
  __syncthreads();

  const int row = blockIdx.x * 64 + lane;
  const float4* hp = (const float4*)(hidden + (size_t)row * HH + seg * 192);
  const float* wsegbase = wt + seg * 192;
  float acc[NL];
#pragma unroll
  for (int l = 0; l < NL; ++l) acc[l] = 0.0f;

#pragma unroll 4
  for (int kb = 0; kb < 48; ++kb) {
    const float4 h4 = hp[kb];
#pragma unroll
    for (int l = 0; l < NL; ++l) {
      const float4 w4 = *(const float4*)(wsegbase + l * HH + kb * 4);
      acc[l] += h4.x * w4.x + h4.y * w4.y + h4.z * w4.z + h4.w * w4.w;
    }
  }
#pragma unroll
  for (int l = 0; l < NL; ++l) part[seg][lane][l] = acc[l];
  __syncthreads();

  for (int idx = tid; idx < 64 * NL; idx += 256) {
    const int r = idx / NL, l = idx - r * NL;
    logits[(size_t)(blockIdx.x * 64 + r) * NL + l] =
        ((part[0][r][l] + part[1][r][l]) + (part[2][r][l] + part[3][r][l])) +
        bias[l];
  }
}

// ---------------------------------------------------------------------------
// Kernel 2: scan kernel, 1664 one-wave blocks.  == R5 VERBATIM (89 us, absmax 0)
//   blk   0..  63 : viterbi (bit-exact ref arithmetic) + backtrace
//   blk  64.. 127 : numerator (gold-path score), parallel over t
//   blk 128..1663 : lognorm segment scans, 3 basis chains per wave
// ---------------------------------------------------------------------------
__global__ __launch_bounds__(64) void scan_kernel(
    const float* __restrict__ logits, const int* __restrict__ labels,
    const float* __restrict__ start_t, const float* __restrict__ end_t,
    const float* __restrict__ trans, float* __restrict__ out,
    float* __restrict__ num_den, const int* __restrict__ lens,
    float* __restrict__ segmat) {
  __shared__ unsigned char bp_s[EMN + 80];
  __shared__ unsigned char tags_s[SS];
  __shared__ int lab[SS];

  const int blk = blockIdx.x;
  const int tid = threadIdx.x;
  const int j   = (tid < NL) ? tid : NL - 1;

  if (blk < 64) {
    // ================= viterbi =================
    const int b   = blk;
    const int len = lens[b];
    const float* emb = logits + (size_t)b * EMN;
    float tc[NL];
#pragma unroll
    for (int i = 0; i < NL; ++i) tc[i] = trans[i * NL + j];
    float s[NL];
#pragma unroll
    for (int i = 0; i < NL; ++i) s[i] = start_t[i] + emb[i];
    float eA = emb[1 * NL + j], eB = emb[2 * NL + j];
    float eC = emb[3 * NL + j], eD = emb[4 * NL + j];
    for (int t = 1; t < len; ++t) {
      float c[NL];
#pragma unroll
      for (int i = 0; i < NL; ++i) c[i] = s[i] + tc[i];
      const float x01 = fmaxf(c[0], c[1]), x23 = fmaxf(c[2], c[3]);
      const float x45 = fmaxf(c[4], c[5]), x67 = fmaxf(c[6], c[7]);
      const float best = fmaxf(fmaxf(fmaxf(x01, x23), fmaxf(x45, x67)), c[8]);
      const float nxt = best + eA;
      {
        const bool b01 = c[0] >= c[1], b23 = c[2] >= c[3];
        const bool b45 = c[4] >= c[5], b67 = c[6] >= c[7];
        const float v01 = b01 ? c[0] : c[1]; const int i01 = b01 ? 0 : 1;
        const float v23 = b23 ? c[2] : c[3]; const int i23 = b23 ? 2 : 3;
        const float v45 = b45 ? c[4] : c[5]; const int i45 = b45 ? 4 : 5;
        const float v67 = b67 ? c[6] : c[7]; const int i67 = b67 ? 6 : 7;
        const bool bA = v01 >= v23, bB = v45 >= v67;
        const float vA = bA ? v01 : v23; const int iA = bA ? i01 : i23;
        const float vB = bB ? v45 : v67; const int iB = bB ? i45 : i67;
        const bool bC = vA >= vB;
        const float vC = bC ? vA : vB; const int iC = bC ? iA : iB;
        const bool bD = vC >= c[8];
        const int arg = bD ? iC : 8;
        bp_s[t * NL + tid] = (unsigned char)arg;   // all lanes; pad-safe
      }
#pragma unroll
      for (int i = 0; i < NL; ++i) s[i] = readlane_f(nxt, i);
      eA = eB; eB = eC; eC = eD;
      eD = emb[(t + 4) * NL + j];   // overrun stays inside ws: safe
    }
    float bv = s[0] + end_t[0];
    int   bl = 0;
#pragma unroll
    for (int i = 1; i < NL; ++i) {
      const float cc = s[i] + end_t[i];
      if (cc > bv) { bv = cc; bl = i; }
    }
    __syncthreads();

    // backtrace: chunked map composition (verified R3..R6)
    uint64_t C = 0x876543210ULL;
#pragma unroll
    for (int k = 1; k <= 8; ++k) {
      const int t = 8 * tid + k;
      uint64_t nc = 0;
#pragma unroll
      for (int x = 0; x < 9; ++x) {
        const int g = bp_s[t * NL + x] & 15;
        nc |= ((C >> (4 * g)) & 15ULL) << (4 * x);
      }
      C = (t < len) ? nc : C;
    }
    const uint32_t Clo = (uint32_t)C, Chi = (uint32_t)(C >> 32);
    uint32_t cur = (uint32_t)bl;
    int bnd = 0;
#pragma unroll
    for (int c = 63; c >= 0; --c) {
      bnd = (tid == c) ? (int)cur : bnd;
      const uint32_t lo = (uint32_t)__builtin_amdgcn_readlane((int)Clo, c);
      const uint32_t hi = (uint32_t)__builtin_amdgcn_readlane((int)Chi, c);
      const uint64_t cc = ((uint64_t)hi << 32) | lo;
      cur = (uint32_t)((cc >> (4 * cur)) & 15u);
    }
    int tag = bnd;
#pragma unroll
    for (int k = 8; k >= 1; --k) {
      const int t = 8 * tid + k;
      const int tt = (t < 512) ? t : 511;
      const int nt = bp_s[tt * NL + tag];
      tag = (t < len) ? nt : tag;
      tags_s[t - 1] = (unsigned char)tag;
    }
    __syncthreads();
    for (int i = tid; i < EMN; i += 64) {
      const int t = i / NL;
      const int l = i - t * NL;
      out[1 + (size_t)b * EMN + i] =
          (t < len && l == (int)tags_s[t]) ? 1.0f : 0.0f;
    }

  } else if (blk < 128) {
    // ================= numerator =================
    const int b   = blk - 64;
    const int len = lens[b];
    const float* emb = logits + (size_t)b * EMN;
    for (int t = tid; t < SS; t += 64) {
      const int v = labels[b * SS + t];
      lab[t] = (v == -100) ? 0 : v;
    }
    __syncthreads();
    float contrib = 0.0f;
    for (int t = tid; t < SS; t += 64) {
      if (t >= 1 && t < len)
        contrib += emb[t * NL + lab[t]] + trans[lab[t - 1] * NL + lab[t]];
    }
#pragma unroll
    for (int off = 32; off >= 1; off >>= 1)
      contrib += __shfl_xor(contrib, off, 64);
    if (tid == 0) {
      const int l0 = lab[0];
      num_den[b] = start_t[l0] + emb[l0] + contrib + end_t[lab[len - 1]];
    }

  } else {
    // ================= lognorm segment scan, 3 chains per wave =================
    const int id   = blk - 128;        // 0..1535
    const int pair = id / 3;
    const int wv   = id - pair * 3;
    const int b    = pair >> 3;
    const int sg   = pair & 7;
    const int e0   = 3 * wv;
    const int len  = lens[b];
    const float* emb = logits + (size_t)b * EMN;
    float tc[NL];
#pragma unroll
    for (int i = 0; i < NL; ++i) tc[i] = trans[i * NL + j];
    float s0[NL], s1[NL], s2[NL];
#pragma unroll
    for (int i = 0; i < NL; ++i) {
      s0[i] = (i == e0)     ? 0.0f : NEG;
      s1[i] = (i == e0 + 1) ? 0.0f : NEG;
      s2[i] = (i == e0 + 2) ? 0.0f : NEG;
    }
    float my0 = (j == e0)     ? 0.0f : NEG;
    float my1 = (j == e0 + 1) ? 0.0f : NEG;
    float my2 = (j == e0 + 2) ? 0.0f : NEG;
    const int tbeg  = 64 * sg + 1;
    const int tlast = (64 * sg + 64 < 511) ? 64 * sg + 64 : 511;
    float eA = emb[tbeg * NL + j],       eB = emb[(tbeg + 1) * NL + j];
    float eC = emb[(tbeg + 2) * NL + j], eD = emb[(tbeg + 3) * NL + j];
    for (int t = tbeg; t <= tlast; ++t) {
      if (t >= len) break;
      float c0[NL], c1[NL], c2[NL];
#pragma unroll
      for (int i = 0; i < NL; ++i) {
        c0[i] = s0[i] + tc[i];
        c1[i] = s1[i] + tc[i];
        c2[i] = s2[i] + tc[i];
      }
      const float m0 = fmaxf(fmaxf(fmaxf(fmaxf(c0[0], c0[1]), fmaxf(c0[2], c0[3])),
                                   fmaxf(fmaxf(c0[4], c0[5]), fmaxf(c0[6], c0[7]))), c0[8]);
      const float m1 = fmaxf(fmaxf(fmaxf(fmaxf(c1[0], c1[1]), fmaxf(c1[2], c1[3])),
                                   fmaxf(fmaxf(c1[4], c1[5]), fmaxf(c1[6], c1[7]))), c1[8]);
      const float m2 = fmaxf(fmaxf(fmaxf(fmaxf(c2[0], c2[1]), fmaxf(c2[2], c2[3])),
                                   fmaxf(fmaxf(c2[4], c2[5]), fmaxf(c2[6], c2[7]))), c2[8]);
      float u0 = 0.0f, u1 = 0.0f, u2 = 0.0f;
#pragma unroll
      for (int i = 0; i < NL; ++i) {
        u0 += __expf(c0[i] - m0);
        u1 += __expf(c1[i] - m1);
        u2 += __expf(c2[i] - m2);
      }
      my0 = m0 + __logf(u0) + eA;
      my1 = m1 + __logf(u1) + eA;
      my2 = m2 + __logf(u2) + eA;
#pragma unroll
      for (int i = 0; i < NL; ++i) {
        s0[i] = readlane_f(my0, i);
        s1[i] = readlane_f(my1, i);
        s2[i] = readlane_f(my2, i);
      }
      eA = eB; eB = eC; eC = eD;
      eD = emb[(t + 4) * NL + j];
    }
    if (tid < NL) {
      float* M = segmat + (size_t)(b * NSEG + sg) * 81;
      M[(e0    ) * NL + tid] = my0;
      M[(e0 + 1) * NL + tid] = my1;
      M[(e0 + 2) * NL + tid] = my2;
    }
  }
}

// ---------------------------------------------------------------------------
// Kernel 3: combine + loss — chain the 8 segment matrices per batch, get
// den = logsumexp(v + end_t), atomically accumulate (den-num)/64.
// ---------------------------------------------------------------------------
__global__ __launch_bounds__(64) void combine_kernel(
    const float* __restrict__ logits, const float* __restrict__ segmat,
    const float* __restrict__ start_t, const float* __restrict__ end_t,
    const float* __restrict__ num_den, float* __restrict__ out) {
  const int b   = blockIdx.x;
  const int tid = threadIdx.x;
  const int j   = (tid < NL) ? tid : NL - 1;
  float s[NL];
#pragma unroll
  for (int i = 0; i < NL; ++i) s[i] = start_t[i] + logits[(size_t)b * EMN + i];
  float mcur[NL], mnxt[NL];
  {
    const float* M = segmat + (size_t)(b * NSEG) * 81;
#pragma unroll
    for (int i = 0; i < NL; ++i) mcur[i] = M[i * NL + j];
  }
  for (int sg = 0; sg < NSEG; ++sg) {
    if (sg + 1 < NSEG) {
      const float* M = segmat + (size_t)(b * NSEG + sg + 1) * 81;
#pragma unroll
      for (int i = 0; i < NL; ++i) mnxt[i] = M[i * NL + j];
    }
    float c[NL];
#pragma unroll
    for (int i = 0; i < NL; ++i) c[i] = s[i] + mcur[i];
    const float x01 = fmaxf(c[0], c[1]), x23 = fmaxf(c[2], c[3]);
    const float x45 = fmaxf(c[4], c[5]), x67 = fmaxf(c[6], c[7]);
    const float m = fmaxf(fmaxf(fmaxf(x01, x23), fmaxf(x45, x67)), c[8]);
    float sum = 0.0f;
#pragma unroll
    for (int i = 0; i < NL; ++i) sum += __expf(c[i] - m);
    const float nxt = m + __logf(sum);
#pragma unroll
    for (int i = 0; i < NL; ++i) s[i] = readlane_f(nxt, i);
#pragma unroll
    for (int i = 0; i < NL; ++i) mcur[i] = mnxt[i];
  }
  float c[NL];
#pragma unroll
  for (int i = 0; i < NL; ++i) c[i] = s[i] + end_t[i];
  const float x01 = fmaxf(c[0], c[1]), x23 = fmaxf(c[2], c[3]);
  const float x45 = fmaxf(c[4], c[5]), x67 = fmaxf(c[6], c[7]);
  const float m = fmaxf(fmaxf(fmaxf(x01, x23), fmaxf(x45, x67)), c[8]);
  float sum = 0.0f;
#pragma unroll
  for (int i = 0; i < NL; ++i) sum += __expf(c[i] - m);
  if (tid == 0) {
    const float den = m + __logf(sum);
    atomicAdd(out, (den - num_den[b]) * (1.0f / 64.0f));
  }
}

extern "C" void kernel_launch(void* const* d_in, const int* in_sizes, int n_in,
                              void* d_out, int out_size, void* d_ws, size_t ws_size,
                              hipStream_t stream) {
  const float* hidden  = (const float*)d_in[0];
  const int*   mask    = (const int*)d_in[1];
  const int*   labels  = (const int*)d_in[2];
  const float* W       = (const float*)d_in[3];
  const float* bias    = (const float*)d_in[4];
  const float* start_t = (const float*)d_in[5];
  const float* end_t   = (const float*)d_in[6];
  const float* trans   = (const float*)d_in[7];
  float* out = (float*)d_out;

  float* logits  = (float*)d_ws;                      // 294912 floats
  float* segmat  = logits + (size_t)NROWS * NL;       // 64*8*81 floats
  float* num_den = segmat + (size_t)BB * NSEG * 81;   // 128 floats
  int*   lens    = (int*)(num_den + 128);             // 64 ints

  hipMemsetAsync(out, 0, sizeof(float), stream);      // zero loss accumulator
  logits_kernel<<<512, 256, 0, stream>>>(hidden, W, bias, mask, logits, lens);
  scan_kernel<<<1664, 64, 0, stream>>>(logits, labels, start_t, end_t, trans,
                                       out, num_den, lens, segmat);
  combine_kernel<<<64, 64, 0, stream>>>(logits, segmat, start_t, end_t,
                                        num_den, out);
}